// Round 2
// baseline (80207.776 us; speedup 1.0000x reference)
//
#include <hip/hip_runtime.h>
#include <math.h>

#define NBLK 256
#define NTHR 512

// ws float offsets
#define OFF_HX  0
#define OFF_CX  8192
#define OFF_H0  16384
#define OFF_CTX 24576
#define OFF_Z   32768            // [4][8][1024]
#define OFF_KB  65536            // [256][8][1024]
#define OFF_VB  (OFF_KB + 2097152)
#define OFF_BAR (OFF_VB + 2097152)   // 2 uints (barrier state, memset per launch)

// LDS float offsets
#define S_WG    0                // 16 rows x 2048 fp32 = 32768 floats
#define S_PART  32768            // 256 (phase A partials; reused phase D: 64)
#define S_H0    33024            // 1024
#define S_Q     34048            // 64
#define S_PS    34112            // 256
#define S_RED   34368            // 8
#define S_RED2  34376            // 8
#define S_CTXP  34384            // 512
#define S_LNS   34896            // 16
#define LDS_FLOATS 34912
#define LDS_BYTES  (LDS_FLOATS * 4)

__device__ __forceinline__ void gsync(unsigned* bar, unsigned* gen) {
    __syncthreads();
    if (threadIdx.x == 0) {
        __threadfence();  // flush this CU/XCD's writes (covers whole block: same CU)
        unsigned g = __hip_atomic_load(gen, __ATOMIC_RELAXED, __HIP_MEMORY_SCOPE_AGENT);
        unsigned a = __hip_atomic_fetch_add(bar, 1u, __ATOMIC_ACQ_REL, __HIP_MEMORY_SCOPE_AGENT);
        if (a == NBLK - 1) {
            __hip_atomic_store(bar, 0u, __ATOMIC_RELAXED, __HIP_MEMORY_SCOPE_AGENT);
            __hip_atomic_store(gen, g + 1u, __ATOMIC_RELEASE, __HIP_MEMORY_SCOPE_AGENT);
        } else {
            while (__hip_atomic_load(gen, __ATOMIC_ACQUIRE, __HIP_MEMORY_SCOPE_AGENT) == g)
                __builtin_amdgcn_s_sleep(2);
        }
        __threadfence();  // invalidate stale lines before this block reads
    }
    __syncthreads();
}

__global__ __launch_bounds__(NTHR, 2)
void qlstm_kernel(const float* __restrict__ x,  const float* __restrict__ Wg,
                  const float* __restrict__ bg, const float* __restrict__ lng,
                  const float* __restrict__ lnb,const float* __restrict__ Wq,
                  const float* __restrict__ Wk, const float* __restrict__ Wv,
                  const float* __restrict__ bq, const float* __restrict__ bk,
                  const float* __restrict__ bv, const float* __restrict__ Wo,
                  const float* __restrict__ bo, float* __restrict__ out,
                  float* __restrict__ ws)
{
    extern __shared__ float lds[];
    const int blk = blockIdx.x, tid = threadIdx.x;
    const int w = tid >> 6, l = tid & 63;

    float* hx  = ws + OFF_HX;   float* cx  = ws + OFF_CX;
    float* h0  = ws + OFF_H0;   float* ctx = ws + OFF_CTX;
    float* z   = ws + OFF_Z;
    float* Kb  = ws + OFF_KB;   float* Vb  = ws + OFF_VB;
    unsigned* bar = (unsigned*)(ws + OFF_BAR);
    unsigned* gen = bar + 1;

    // ---- preload Wg slice (16 rows x 2048 fp32) into LDS ----
    {
        const float* wsrc = Wg + (size_t)blk * 16 * 2048;
        #pragma unroll
        for (int j = 0; j < 16; ++j) {
            float4 v = *(const float4*)(wsrc + j * 2048 + tid * 4);
            *(float4*)(lds + S_WG + j * 2048 + tid * 4) = v;
        }
    }
    // ---- preload K/V-proj weights: 1 row per wave, spread over lanes (VGPRs) ----
    const int kv_row = blk * 8 + w;             // 0..2047  ([Wk;Wv] rows)
    const int kv_mat = kv_row >> 10;            // 0 = K, 1 = V
    const int kv_h   = kv_row & 1023;
    const float* kv_wrow = (kv_mat ? Wv : Wk) + (size_t)kv_h * 1024;
    float4 wkv[4];
    #pragma unroll
    for (int i = 0; i < 4; ++i) wkv[i] = *(const float4*)(kv_wrow + i * 256 + l * 4);
    const float kv_bias = (kv_mat ? bv : bk)[kv_h];
    // ---- preload Wo slice: 4 rows/block, 2 waves per row (k-halves) ----
    const int o_row = blk * 4 + (w >> 1);
    const int o_hf  = w & 1;
    float4 wo[2];
    #pragma unroll
    for (int i = 0; i < 2; ++i)
        wo[i] = *(const float4*)(Wo + (size_t)o_row * 1024 + o_hf * 512 + i * 256 + l * 4);

    // ---- zero hx, cx ----
    { const int idx = blk * NTHR + tid; if (idx < 16384) ws[idx] = 0.f; }
    gsync(bar, gen);

    for (int t = 0; t < 256; ++t) {
        // ================= Phase A: z-GEMV (LDS weights) + KV-proj (VGPR weights) =================
        {
            const int g4 = w & 3, hh = w >> 2;          // rowgroup, k-half
            const float* asrc = hh ? hx : (x + (size_t)t * 8192);
            float acc[4][8];
            #pragma unroll
            for (int r = 0; r < 4; ++r)
                #pragma unroll
                for (int b = 0; b < 8; ++b) acc[r][b] = 0.f;
            #pragma unroll
            for (int i = 0; i < 4; ++i) {
                const int kk = i * 256 + l * 4;         // offset within the 1024-half
                float4 a4[8];
                #pragma unroll
                for (int b = 0; b < 8; ++b) a4[b] = *(const float4*)(asrc + b * 1024 + kk);
                #pragma unroll
                for (int r = 0; r < 4; ++r) {
                    const float4 w4 = *(const float4*)(lds + S_WG + (g4 * 4 + r) * 2048 + hh * 1024 + kk);
                    #pragma unroll
                    for (int b = 0; b < 8; ++b)
                        acc[r][b] += w4.x*a4[b].x + w4.y*a4[b].y + w4.z*a4[b].z + w4.w*a4[b].w;
                }
            }
            #pragma unroll
            for (int o = 1; o < 64; o <<= 1)
                #pragma unroll
                for (int r = 0; r < 4; ++r)
                    #pragma unroll
                    for (int b = 0; b < 8; ++b) acc[r][b] += __shfl_xor(acc[r][b], o);
            if (l == 0) {
                #pragma unroll
                for (int r = 0; r < 4; ++r)
                    #pragma unroll
                    for (int b = 0; b < 8; ++b)
                        lds[S_PART + (g4 * 4 + r) * 16 + hh * 8 + b] = acc[r][b];
            }
            // KV projection of hx(t-1) -> Kb/Vb[t-1]
            if (t > 0) {
                float a2[8];
                #pragma unroll
                for (int b = 0; b < 8; ++b) a2[b] = 0.f;
                #pragma unroll
                for (int i = 0; i < 4; ++i) {
                    const int kk = i * 256 + l * 4;
                    #pragma unroll
                    for (int b = 0; b < 8; ++b) {
                        const float4 h4 = *(const float4*)(hx + b * 1024 + kk);
                        a2[b] += wkv[i].x*h4.x + wkv[i].y*h4.y + wkv[i].z*h4.z + wkv[i].w*h4.w;
                    }
                }
                #pragma unroll
                for (int o = 1; o < 64; o <<= 1)
                    #pragma unroll
                    for (int b = 0; b < 8; ++b) a2[b] += __shfl_xor(a2[b], o);
                if (l == 0) {
                    float* dst = kv_mat ? Vb : Kb;
                    #pragma unroll
                    for (int b = 0; b < 8; ++b)
                        dst[((size_t)(t - 1) * 8 + b) * 1024 + kv_h] = a2[b] + kv_bias;
                }
            }
            __syncthreads();
            if (tid < 128) {
                const int lr = tid >> 3, b = tid & 7;
                const int gg = blk >> 6, h = (blk & 63) * 16 + lr;
                const float zv = lds[S_PART + lr * 16 + b] + lds[S_PART + lr * 16 + 8 + b]
                               + bg[gg * 1024 + h];
                z[((size_t)gg * 8 + b) * 1024 + h] = zv;
            }
        }
        gsync(bar, gen);
        // ================= Phase B: LN + gates + cell update (blocks 0..7) =================
        if (blk < 8) {
            const int b = blk, gt = w & 3, hf = w >> 2;
            const float* zr = z + ((size_t)gt * 8 + b) * 1024 + hf * 512;
            float s = 0.f, q = 0.f;
            #pragma unroll
            for (int j = 0; j < 8; ++j) { const float v = zr[j * 64 + l]; s += v; q += v * v; }
            #pragma unroll
            for (int o = 1; o < 64; o <<= 1) { s += __shfl_xor(s, o); q += __shfl_xor(q, o); }
            if (l == 0) { lds[S_LNS + w] = s; lds[S_LNS + 8 + w] = q; }
            __syncthreads();
            float mean[4], rstd[4];
            #pragma unroll
            for (int g2 = 0; g2 < 4; ++g2) {
                const float ssum = lds[S_LNS + g2] + lds[S_LNS + 4 + g2];
                const float qsum = lds[S_LNS + 8 + g2] + lds[S_LNS + 12 + g2];
                const float m = ssum * (1.f / 1024.f);
                mean[g2] = m;
                rstd[g2] = rsqrtf(qsum * (1.f / 1024.f) - m * m + 1e-5f);
            }
            #pragma unroll
            for (int jj = 0; jj < 2; ++jj) {
                const int h = jj * 512 + tid;
                float zv[4];
                #pragma unroll
                for (int g2 = 0; g2 < 4; ++g2) {
                    const float v = z[((size_t)g2 * 8 + b) * 1024 + h];
                    zv[g2] = (v - mean[g2]) * rstd[g2] * lng[g2 * 1024 + h] + lnb[g2 * 1024 + h];
                }
                const float f  = 1.f / (1.f + __expf(-zv[0]));
                const float ii = 1.f / (1.f + __expf(-zv[1]));
                const float gg = tanhf(zv[2]);
                const float oo = 1.f / (1.f + __expf(-zv[3]));
                const float c  = f * cx[b * 1024 + h] + ii * gg;
                cx[b * 1024 + h] = c;
                h0[b * 1024 + h] = oo * tanhf(c);
            }
        }
        gsync(bar, gen);
        // ================= Phase C: q-proj + attention (blocks 0..127, t>0) =================
        if (blk < 128 && t > 0) {
            const int b = blk >> 4, nh = blk & 15;
            lds[S_H0 + tid]       = h0[b * 1024 + tid];
            lds[S_H0 + 512 + tid] = h0[b * 1024 + 512 + tid];
            __syncthreads();
            {   // q projection: 64 rows, k-split 8
                const int dh = tid >> 3, ks = tid & 7;
                const float* wrow = Wq + (size_t)(nh * 64 + dh) * 1024;
                float qa = 0.f;
                #pragma unroll 8
                for (int i = 0; i < 32; ++i) {
                    const int k = i * 32 + ks * 4;
                    const float4 w4 = *(const float4*)(wrow + k);
                    const float4 a4 = *(const float4*)(lds + S_H0 + k);
                    qa += w4.x*a4.x + w4.y*a4.y + w4.z*a4.z + w4.w*a4.w;
                }
                qa += __shfl_xor(qa, 1); qa += __shfl_xor(qa, 2); qa += __shfl_xor(qa, 4);
                if (ks == 0) lds[S_Q + dh] = (qa + bq[nh * 64 + dh]) * 0.125f;
            }
            __syncthreads();
            float sc = -1e30f;
            if (tid < t) {
                const float* kr = Kb + ((size_t)tid * 8 + b) * 1024 + nh * 64;
                float d = 0.f;
                #pragma unroll
                for (int j = 0; j < 16; ++j) {
                    const float4 k4 = *(const float4*)(kr + j * 4);
                    d += k4.x*lds[S_Q + j*4] + k4.y*lds[S_Q + j*4+1]
                       + k4.z*lds[S_Q + j*4+2] + k4.w*lds[S_Q + j*4+3];
                }
                sc = d;
            }
            float mx = sc;
            #pragma unroll
            for (int o = 1; o < 64; o <<= 1) mx = fmaxf(mx, __shfl_xor(mx, o));
            if (l == 0) lds[S_RED + w] = mx;
            __syncthreads();
            mx = lds[S_RED];
            #pragma unroll
            for (int j = 1; j < 8; ++j) mx = fmaxf(mx, lds[S_RED + j]);
            const float p = (tid < t) ? __expf(sc - mx) : 0.f;
            if (tid < 256) lds[S_PS + tid] = p;
            float psum = p;
            #pragma unroll
            for (int o = 1; o < 64; o <<= 1) psum += __shfl_xor(psum, o);
            if (l == 0) lds[S_RED2 + w] = psum;
            __syncthreads();
            float tot = lds[S_RED2];
            #pragma unroll
            for (int j = 1; j < 8; ++j) tot += lds[S_RED2 + j];
            const float inv = 1.f / tot;
            const int dh2 = tid & 63, ss = tid >> 6;
            float ca = 0.f;
            for (int s = ss; s < t; s += 8)
                ca += lds[S_PS + s] * Vb[((size_t)s * 8 + b) * 1024 + nh * 64 + dh2];
            lds[S_CTXP + tid] = ca;
            __syncthreads();
            if (tid < 64) {
                float v = 0.f;
                #pragma unroll
                for (int j = 0; j < 8; ++j) v += lds[S_CTXP + j * 64 + tid];
                ctx[b * 1024 + nh * 64 + tid] = v * inv;
            }
        }
        gsync(bar, gen);
        // ================= Phase D: out-proj (VGPR Wo) + hx update + emit (all blocks) ==========
        {
            float acc[8];
            #pragma unroll
            for (int b = 0; b < 8; ++b) acc[b] = 0.f;
            #pragma unroll
            for (int i = 0; i < 2; ++i) {
                const int k = o_hf * 512 + i * 256 + l * 4;
                #pragma unroll
                for (int b = 0; b < 8; ++b) {
                    const float4 c4 = *(const float4*)(ctx + b * 1024 + k);
                    acc[b] += wo[i].x*c4.x + wo[i].y*c4.y + wo[i].z*c4.z + wo[i].w*c4.w;
                }
            }
            #pragma unroll
            for (int o = 1; o < 64; o <<= 1)
                #pragma unroll
                for (int b = 0; b < 8; ++b) acc[b] += __shfl_xor(acc[b], o);
            if (l == 0) {
                #pragma unroll
                for (int b = 0; b < 8; ++b) lds[S_PART + w * 8 + b] = acc[b];
            }
            __syncthreads();
            if (tid < 32) {
                const int rr = tid >> 3, b = tid & 7;
                const int r  = blk * 4 + rr;
                float v = h0[b * 1024 + r];
                if (t > 0)
                    v += lds[S_PART + (rr * 2) * 8 + b] + lds[S_PART + (rr * 2 + 1) * 8 + b] + bo[r];
                hx[b * 1024 + r] = v;
                out[(size_t)t * 8192 + b * 1024 + r] = v;
            }
        }
        gsync(bar, gen);
    }

    // epilogue: final hx, cx
    if (blk < 8) {
        for (int h = tid; h < 1024; h += NTHR)
            out[2097152 + blk * 1024 + h] = hx[blk * 1024 + h];
    } else if (blk < 16) {
        const int b = blk - 8;
        for (int h = tid; h < 1024; h += NTHR)
            out[2097152 + 8192 + b * 1024 + h] = cx[b * 1024 + h];
    }
}

extern "C" void kernel_launch(void* const* d_in, const int* in_sizes, int n_in,
                              void* d_out, int out_size, void* d_ws, size_t ws_size,
                              hipStream_t stream) {
    const float* x   = (const float*)d_in[0];
    const float* Wg  = (const float*)d_in[1];
    const float* bg  = (const float*)d_in[2];
    const float* lng = (const float*)d_in[3];
    const float* lnb = (const float*)d_in[4];
    const float* Wq  = (const float*)d_in[5];
    const float* Wk  = (const float*)d_in[6];
    const float* Wv  = (const float*)d_in[7];
    const float* bq  = (const float*)d_in[8];
    const float* bk  = (const float*)d_in[9];
    const float* bv  = (const float*)d_in[10];
    const float* Wo  = (const float*)d_in[11];
    const float* bo  = (const float*)d_in[12];
    float* out = (float*)d_out;
    float* ws  = (float*)d_ws;

    static int attr_set = 0;
    if (!attr_set) {
        hipFuncSetAttribute((const void*)qlstm_kernel,
                            hipFuncAttributeMaxDynamicSharedMemorySize, LDS_BYTES);
        attr_set = 1;
    }
    // reset grid barrier (deterministic per launch; captured into the graph)
    hipMemsetAsync((char*)d_ws + (size_t)OFF_BAR * 4, 0, 8, stream);

    void* args[] = { &x, &Wg, &bg, &lng, &lnb, &Wq, &Wk, &Wv,
                     &bq, &bk, &bv, &Wo, &bo, &out, &ws };
    hipLaunchCooperativeKernel((void*)qlstm_kernel, dim3(NBLK), dim3(NTHR),
                               args, LDS_BYTES, stream);
}

// Round 4
// 17986.221 us; speedup vs baseline: 4.4594x; 4.4594x over previous
//
#include <hip/hip_runtime.h>
#include <math.h>

#define NBLK 256
#define NTHR 512

// ws float offsets (all cross-block data accessed via device-scope sc1 ops)
#define OFF_HX  0               // [8][1024]
#define OFF_H0  8192            // [8][1024]
#define OFF_CTX 16384           // [8][1024]
#define OFF_Z   24576           // [4][8][1024]
#define OFF_Q   57344           // [8][1024]
#define OFF_KB  65536           // [256][8][1024]
#define OFF_VB  (OFF_KB + 2097152)
#define OFF_BAR (OFF_VB + 2097152)   // 1 uint (memset 0 per launch)

// LDS float offsets
#define S_WG    0                // 16 rows x 2048 fp32
#define S_HX    32768            // 4096 (16KB hx staging chunk)
#define S_CX    36864            // 1024 (persistent cx, blocks 0..7)
#define S_RED   37888            // 32
#define S_Q     37920            // 64
#define S_PS    37984            // 256
#define S_R2    38240            // 16
#define S_CTXP  38256            // 512
#define LDS_FLOATS 38768
#define LDS_BYTES  (LDS_FLOATS * 4)

typedef unsigned long long u64;
union F2U { u64 u; float2 f; };

__device__ __forceinline__ float ld1(const float* p) {
    return __hip_atomic_load(const_cast<float*>(p), __ATOMIC_RELAXED, __HIP_MEMORY_SCOPE_AGENT);
}
__device__ __forceinline__ void st1(float* p, float v) {
    __hip_atomic_store(p, v, __ATOMIC_RELAXED, __HIP_MEMORY_SCOPE_AGENT);
}
__device__ __forceinline__ float2 ld2(const float* p) {
    F2U c; c.u = __hip_atomic_load(reinterpret_cast<u64*>(const_cast<float*>(p)),
                                   __ATOMIC_RELAXED, __HIP_MEMORY_SCOPE_AGENT);
    return c.f;
}
__device__ __forceinline__ float4 ld4(const float* p) {
    float2 a = ld2(p), b = ld2(p + 2);
    return make_float4(a.x, a.y, b.x, b.y);
}
__device__ __forceinline__ float dot4(const float4 a, const float4 b) {
    return a.x*b.x + a.y*b.y + a.z*b.z + a.w*b.w;
}

// Monotonic relaxed-atomic grid barrier. No acquire/release fences: all
// cross-block data is sc1 (MALL-coherent), and __syncthreads drains each
// wave's vmcnt before s_barrier, so stores are globally visible pre-arrival.
__device__ __forceinline__ void gsync(unsigned* bar, unsigned target) {
    __syncthreads();
    if (threadIdx.x == 0) {
        asm volatile("" ::: "memory");
        __hip_atomic_fetch_add(bar, 1u, __ATOMIC_RELAXED, __HIP_MEMORY_SCOPE_AGENT);
        while (__hip_atomic_load(bar, __ATOMIC_RELAXED, __HIP_MEMORY_SCOPE_AGENT) < target)
            __builtin_amdgcn_s_sleep(2);
        asm volatile("" ::: "memory");
    }
    __syncthreads();
}

__global__ __launch_bounds__(NTHR, 1)
void qlstm_kernel(const float* __restrict__ x,  const float* __restrict__ Wg,
                  const float* __restrict__ bg, const float* __restrict__ lng,
                  const float* __restrict__ lnb,const float* __restrict__ Wq,
                  const float* __restrict__ Wk, const float* __restrict__ Wv,
                  const float* __restrict__ bq, const float* __restrict__ bk,
                  const float* __restrict__ bv, const float* __restrict__ Wo,
                  const float* __restrict__ bo, float* __restrict__ out,
                  float* __restrict__ ws)
{
    extern __shared__ float lds[];
    const int blk = blockIdx.x, tid = threadIdx.x;
    const int w = tid >> 6, l = tid & 63;

    float* hx  = ws + OFF_HX;   float* h0 = ws + OFF_H0;
    float* ctx = ws + OFF_CTX;  float* z  = ws + OFF_Z;
    float* qb  = ws + OFF_Q;
    float* Kb  = ws + OFF_KB;   float* Vb = ws + OFF_VB;
    unsigned* bar = (unsigned*)(ws + OFF_BAR);
    unsigned bcnt = 0;

    // ---- preload Wg slice (16 rows x 2048 fp32) into LDS (normal cached loads) ----
    {
        const float* wsrc = Wg + (size_t)blk * 32768;
        #pragma unroll
        for (int j = 0; j < 16; ++j) {
            const int fi = j * 512 + tid;           // float4 index
            *(float4*)(lds + S_WG + fi * 4) = *(const float4*)(wsrc + fi * 4);
        }
    }
    // ---- K/V-proj weights: 1 row per wave, in VGPRs ----
    const int kv_row = blk * 8 + w;
    const int kv_mat = kv_row >> 10, kv_h = kv_row & 1023;
    const float* kv_wrow = (kv_mat ? Wv : Wk) + (size_t)kv_h * 1024;
    float4 wkv[4];
    #pragma unroll
    for (int i = 0; i < 4; ++i) wkv[i] = *(const float4*)(kv_wrow + i * 256 + l * 4);
    const float kv_bias = (kv_mat ? bv : bk)[kv_h];
    // ---- gate bias for this block's 2 rows per wave (block covers one gate g) ----
    const int g  = blk >> 6;
    const int h0r = (blk & 63) * 16 + 2 * w;        // global h of wave's row 0
    const float bg0 = bg[g * 1024 + h0r], bg1 = bg[g * 1024 + h0r + 1];
    // ---- q/out proj row assignment: rows blk*4..+3, wave = batch ----
    const float bq0 = bq[blk*4+0], bq1 = bq[blk*4+1], bq2 = bq[blk*4+2], bq3 = bq[blk*4+3];
    const float bo0 = bo[blk*4+0], bo1 = bo[blk*4+1], bo2 = bo[blk*4+2], bo3 = bo[blk*4+3];

    // ---- init: zero hx (sc1 so readers see it), zero LDS cx ----
    { const int idx = blk * NTHR + tid; if (idx < 8192) st1(hx + idx, 0.f); }
    if (blk < 8) { if (tid < 256) { *(float4*)(lds + S_CX + tid * 4) = make_float4(0,0,0,0); } }
    gsync(bar, ++bcnt * NBLK);

    for (int t = 0; t < 256; ++t) {
        // ========== Phase A: gate GEMV (x-part + staged-hx part) + KV proj ==========
        {
            float a0[8], a1[8], akv[8];
            #pragma unroll
            for (int b = 0; b < 8; ++b) { a0[b] = 0.f; a1[b] = 0.f; akv[b] = 0.f; }
            const float* xt = x + (size_t)t * 8192;
            #pragma unroll
            for (int i = 0; i < 4; ++i) {            // x-part (normal cached loads)
                const int k = i * 256 + l * 4;
                const float4 w0 = *(const float4*)(lds + S_WG + (2*w)   * 2048 + k);
                const float4 w1 = *(const float4*)(lds + S_WG + (2*w+1) * 2048 + k);
                #pragma unroll
                for (int b = 0; b < 8; ++b) {
                    const float4 a = *(const float4*)(xt + b * 1024 + k);
                    a0[b] += dot4(w0, a); a1[b] += dot4(w1, a);
                }
            }
            if (t > 0) {                              // hx-part via LDS staging chunks
                #pragma unroll
                for (int c = 0; c < 2; ++c) {
                    __syncthreads();
                    #pragma unroll
                    for (int j = 0; j < 4; ++j) {
                        const int fi = tid * 8 + j * 2;
                        const int b = fi >> 9, off = fi & 511;
                        *(float2*)(lds + S_HX + fi) = ld2(hx + b * 1024 + c * 512 + off);
                    }
                    __syncthreads();
                    #pragma unroll
                    for (int ii = 0; ii < 2; ++ii) {
                        const int i = c * 2 + ii;
                        const int k = i * 256 + l * 4;
                        const float4 w0 = *(const float4*)(lds + S_WG + (2*w)   * 2048 + 1024 + k);
                        const float4 w1 = *(const float4*)(lds + S_WG + (2*w+1) * 2048 + 1024 + k);
                        const float4 wk = wkv[i];
                        #pragma unroll
                        for (int b = 0; b < 8; ++b) {
                            const float4 a = *(const float4*)(lds + S_HX + b * 512 + ii * 256 + l * 4);
                            a0[b] += dot4(w0, a); a1[b] += dot4(w1, a); akv[b] += dot4(wk, a);
                        }
                    }
                }
            }
            #pragma unroll
            for (int o = 1; o < 64; o <<= 1)
                #pragma unroll
                for (int b = 0; b < 8; ++b) {
                    a0[b] += __shfl_xor(a0[b], o);
                    a1[b] += __shfl_xor(a1[b], o);
                    akv[b] += __shfl_xor(akv[b], o);
                }
            if (l == 0) {
                #pragma unroll
                for (int b = 0; b < 8; ++b) {
                    st1(z + (size_t)(g * 8 + b) * 1024 + h0r,     a0[b] + bg0);
                    st1(z + (size_t)(g * 8 + b) * 1024 + h0r + 1, a1[b] + bg1);
                }
                if (t > 0) {
                    float* dst = kv_mat ? Vb : Kb;
                    #pragma unroll
                    for (int b = 0; b < 8; ++b)
                        st1(dst + ((size_t)(t - 1) * 8 + b) * 1024 + kv_h, akv[b] + kv_bias);
                }
            }
        }
        gsync(bar, ++bcnt * NBLK);
        // ========== Phase B: LN + gates + cell update (blocks 0..7, cx in LDS) ==========
        if (blk < 8) {
            const int b = blk, gt = w >> 1, hf = w & 1;
            const float* zr = z + ((size_t)gt * 8 + b) * 1024 + hf * 512;
            float s = 0.f, q = 0.f;
            #pragma unroll
            for (int j = 0; j < 8; ++j) { const float v = ld1(zr + j * 64 + l); s += v; q += v * v; }
            #pragma unroll
            for (int o = 1; o < 64; o <<= 1) { s += __shfl_xor(s, o); q += __shfl_xor(q, o); }
            if (l == 0) { lds[S_RED + w] = s; lds[S_RED + 8 + w] = q; }
            __syncthreads();
            float mean[4], rstd[4];
            #pragma unroll
            for (int g2 = 0; g2 < 4; ++g2) {
                const float ss = lds[S_RED + 2*g2] + lds[S_RED + 2*g2 + 1];
                const float qq = lds[S_RED + 8 + 2*g2] + lds[S_RED + 8 + 2*g2 + 1];
                const float m = ss * (1.f / 1024.f);
                mean[g2] = m;
                rstd[g2] = rsqrtf(qq * (1.f / 1024.f) - m * m + 1e-5f);
            }
            #pragma unroll
            for (int jj = 0; jj < 2; ++jj) {
                const int h = jj * 512 + tid;
                float zv[4];
                #pragma unroll
                for (int g2 = 0; g2 < 4; ++g2) {
                    const float v = ld1(z + ((size_t)g2 * 8 + b) * 1024 + h);
                    zv[g2] = (v - mean[g2]) * rstd[g2] * lng[g2 * 1024 + h] + lnb[g2 * 1024 + h];
                }
                const float f  = 1.f / (1.f + __expf(-zv[0]));
                const float ii = 1.f / (1.f + __expf(-zv[1]));
                const float gg = tanhf(zv[2]);
                const float oo = 1.f / (1.f + __expf(-zv[3]));
                const float c  = f * lds[S_CX + h] + ii * gg;
                lds[S_CX + h] = c;
                st1(h0 + b * 1024 + h, oo * tanhf(c));
            }
        }
        gsync(bar, ++bcnt * NBLK);
        // ========== Phase C: q-projection (all blocks; wave = batch, 4 rows) ==========
        {
            const int b = w;
            const float* hb = h0 + b * 1024;
            float q0 = 0.f, q1 = 0.f, q2 = 0.f, q3 = 0.f;
            #pragma unroll
            for (int i = 0; i < 4; ++i) {
                const int k = i * 256 + l * 4;
                const float4 h4 = ld4(hb + k);
                const float4 w0 = *(const float4*)(Wq + (size_t)(blk*4+0) * 1024 + k);
                const float4 w1 = *(const float4*)(Wq + (size_t)(blk*4+1) * 1024 + k);
                const float4 w2 = *(const float4*)(Wq + (size_t)(blk*4+2) * 1024 + k);
                const float4 w3 = *(const float4*)(Wq + (size_t)(blk*4+3) * 1024 + k);
                q0 += dot4(w0, h4); q1 += dot4(w1, h4); q2 += dot4(w2, h4); q3 += dot4(w3, h4);
            }
            #pragma unroll
            for (int o = 1; o < 64; o <<= 1) {
                q0 += __shfl_xor(q0, o); q1 += __shfl_xor(q1, o);
                q2 += __shfl_xor(q2, o); q3 += __shfl_xor(q3, o);
            }
            if (l == 0) {
                st1(qb + b * 1024 + blk*4 + 0, (q0 + bq0) * 0.125f);
                st1(qb + b * 1024 + blk*4 + 1, (q1 + bq1) * 0.125f);
                st1(qb + b * 1024 + blk*4 + 2, (q2 + bq2) * 0.125f);
                st1(qb + b * 1024 + blk*4 + 3, (q3 + bq3) * 0.125f);
            }
        }
        gsync(bar, ++bcnt * NBLK);
        // ========== Phase D: attention (blocks 0..127, t>0) ==========
        if (blk < 128 && t > 0) {
            const int b = blk >> 4, nh = blk & 15;
            if (tid < 32) *(float2*)(lds + S_Q + tid * 2) = ld2(qb + b * 1024 + nh * 64 + tid * 2);
            __syncthreads();
            float sc = -1e30f;
            if (tid < t) {
                const float* kr = Kb + ((size_t)tid * 8 + b) * 1024 + nh * 64;
                float d = 0.f;
                #pragma unroll
                for (int j = 0; j < 32; ++j) {
                    const float2 k2 = ld2(kr + j * 2);
                    d += k2.x * lds[S_Q + j*2] + k2.y * lds[S_Q + j*2 + 1];
                }
                sc = d;
            }
            float mx = sc;
            #pragma unroll
            for (int o = 1; o < 64; o <<= 1) mx = fmaxf(mx, __shfl_xor(mx, o));
            if (l == 0) lds[S_RED + w] = mx;
            __syncthreads();
            mx = lds[S_RED];
            #pragma unroll
            for (int j = 1; j < 8; ++j) mx = fmaxf(mx, lds[S_RED + j]);
            const float p = (tid < t) ? __expf(sc - mx) : 0.f;
            if (tid < 256) lds[S_PS + tid] = p;
            float ps = p;
            #pragma unroll
            for (int o = 1; o < 64; o <<= 1) ps += __shfl_xor(ps, o);
            if (l == 0) lds[S_R2 + w] = ps;
            __syncthreads();
            float tot = lds[S_R2];
            #pragma unroll
            for (int j = 1; j < 8; ++j) tot += lds[S_R2 + j];
            const float inv = 1.f / tot;
            const int dh = tid & 63, ss = tid >> 6;
            float ca = 0.f;
            for (int s = ss; s < t; s += 8)
                ca += lds[S_PS + s] * ld1(Vb + ((size_t)s * 8 + b) * 1024 + nh * 64 + dh);
            lds[S_CTXP + tid] = ca;
            __syncthreads();
            if (tid < 64) {
                float v = 0.f;
                #pragma unroll
                for (int j = 0; j < 8; ++j) v += lds[S_CTXP + j * 64 + tid];
                st1(ctx + b * 1024 + nh * 64 + tid, v * inv);
            }
        }
        gsync(bar, ++bcnt * NBLK);
        // ========== Phase E: out-proj + hx update + emit (all blocks; wave = batch) ==========
        {
            const int b = w;
            const float* cb = ctx + b * 1024;
            float o0 = 0.f, o1 = 0.f, o2 = 0.f, o3 = 0.f;
            #pragma unroll
            for (int i = 0; i < 4; ++i) {
                const int k = i * 256 + l * 4;
                const float4 c4 = ld4(cb + k);
                const float4 w0 = *(const float4*)(Wo + (size_t)(blk*4+0) * 1024 + k);
                const float4 w1 = *(const float4*)(Wo + (size_t)(blk*4+1) * 1024 + k);
                const float4 w2 = *(const float4*)(Wo + (size_t)(blk*4+2) * 1024 + k);
                const float4 w3 = *(const float4*)(Wo + (size_t)(blk*4+3) * 1024 + k);
                o0 += dot4(w0, c4); o1 += dot4(w1, c4); o2 += dot4(w2, c4); o3 += dot4(w3, c4);
            }
            #pragma unroll
            for (int o = 1; o < 64; o <<= 1) {
                o0 += __shfl_xor(o0, o); o1 += __shfl_xor(o1, o);
                o2 += __shfl_xor(o2, o); o3 += __shfl_xor(o3, o);
            }
            if (l == 0) {
                const float h0v0 = ld1(h0 + b * 1024 + blk*4 + 0);
                const float h0v1 = ld1(h0 + b * 1024 + blk*4 + 1);
                const float h0v2 = ld1(h0 + b * 1024 + blk*4 + 2);
                const float h0v3 = ld1(h0 + b * 1024 + blk*4 + 3);
                const float v0 = (t > 0) ? h0v0 + o0 + bo0 : h0v0;
                const float v1 = (t > 0) ? h0v1 + o1 + bo1 : h0v1;
                const float v2 = (t > 0) ? h0v2 + o2 + bo2 : h0v2;
                const float v3 = (t > 0) ? h0v3 + o3 + bo3 : h0v3;
                st1(hx + b * 1024 + blk*4 + 0, v0);
                st1(hx + b * 1024 + blk*4 + 1, v1);
                st1(hx + b * 1024 + blk*4 + 2, v2);
                st1(hx + b * 1024 + blk*4 + 3, v3);
                float* op = out + (size_t)t * 8192 + b * 1024 + blk * 4;
                op[0] = v0; op[1] = v1; op[2] = v2; op[3] = v3;
            }
        }
        gsync(bar, ++bcnt * NBLK);
    }

    // epilogue: final hx, cx
    if (blk < 8) {
        for (int h = tid; h < 1024; h += NTHR)
            out[2097152 + 8192 + blk * 1024 + h] = lds[S_CX + h];
    } else if (blk < 16) {
        const int b = blk - 8;
        for (int h = tid; h < 1024; h += NTHR)
            out[2097152 + b * 1024 + h] = ld1(hx + b * 1024 + h);
    }
}

extern "C" void kernel_launch(void* const* d_in, const int* in_sizes, int n_in,
                              void* d_out, int out_size, void* d_ws, size_t ws_size,
                              hipStream_t stream) {
    const float* x   = (const float*)d_in[0];
    const float* Wg  = (const float*)d_in[1];
    const float* bg  = (const float*)d_in[2];
    const float* lng = (const float*)d_in[3];
    const float* lnb = (const float*)d_in[4];
    const float* Wq  = (const float*)d_in[5];
    const float* Wk  = (const float*)d_in[6];
    const float* Wv  = (const float*)d_in[7];
    const float* bq  = (const float*)d_in[8];
    const float* bk  = (const float*)d_in[9];
    const float* bv  = (const float*)d_in[10];
    const float* Wo  = (const float*)d_in[11];
    const float* bo  = (const float*)d_in[12];
    float* out = (float*)d_out;
    float* ws  = (float*)d_ws;

    static int attr_set = 0;
    if (!attr_set) {
        hipFuncSetAttribute((const void*)qlstm_kernel,
                            hipFuncAttributeMaxDynamicSharedMemorySize, LDS_BYTES);
        attr_set = 1;
    }
    // reset barrier counter (graph-captured; deterministic per replay)
    hipMemsetAsync((char*)d_ws + (size_t)OFF_BAR * 4, 0, 4, stream);

    void* args[] = { &x, &Wg, &bg, &lng, &lnb, &Wq, &Wk, &Wv,
                     &bq, &bk, &bv, &Wo, &bo, &out, &ws };
    hipLaunchCooperativeKernel((void*)qlstm_kernel, dim3(NBLK), dim3(NTHR),
                               args, LDS_BYTES, stream);
}